// Round 1
// baseline (1990.245 us; speedup 1.0000x reference)
//
#include <hip/hip_runtime.h>
#include <hip/hip_fp16.h>

#define S_LEN 512
#define BATCH 32
#define WIN 5
#define EMBD 300
#define HDIM 300

typedef _Float16 hv2 __attribute__((ext_vector_type(2)));

__device__ __forceinline__ float dot2f(hv2 a, hv2 b, float c) {
#if __has_builtin(__builtin_amdgcn_fdot2)
    return __builtin_amdgcn_fdot2(a, b, c, false);
#else
    return c + (float)a.x * (float)b.x + (float)a.y * (float)b.y;
#endif
}

__device__ __forceinline__ float fast_tanh(float x) {
    // tanh(x) = 1 - 2/(e^{2x}+1); exact at +-inf, ~1e-7 rel err
    float e = __expf(2.f * x);
    return 1.f - 2.f / (e + 1.f);
}

// ---------------------------------------------------------------------------
// GEMM1 (fused embedding gather + relu):
//   U[(t*32+b)*300 + n] = sum_{w,c} relu(emb[x[b,t,w]][c]) * W_ih1[n][w*300+c]
//                          + b_ih1[n] + b_hh1[n]
// grid (512, 3) : x = t, y = n-block (128 cols); block 256 = 8 row-groups x 32 col-groups
// ---------------------------------------------------------------------------
__global__ __launch_bounds__(256) void k_gemm1(
    const int* __restrict__ x, const float* __restrict__ emb,
    const float* __restrict__ Wih1, const float* __restrict__ b_ih1,
    const float* __restrict__ b_hh1, float* __restrict__ U)
{
    const int t   = blockIdx.x;
    const int n0  = blockIdx.y * 128;
    const int tid = threadIdx.x;
    const int bg  = tid >> 5;   // 0..7 -> rows 4bg..4bg+3 (batch)
    const int ng  = tid & 31;   // 0..31 -> cols n0+4ng..+3

    __shared__ __align__(16) float As[32][300];

    float acc[4][4];
    #pragma unroll
    for (int i = 0; i < 4; ++i)
        #pragma unroll
        for (int j = 0; j < 4; ++j) acc[i][j] = 0.f;

    size_t woff[4];
    #pragma unroll
    for (int j = 0; j < 4; ++j) {
        int n = n0 + 4 * ng + j;
        if (n > 299) n = 299;          // clamp (results discarded at store)
        woff[j] = (size_t)n * 1500;
    }

    for (int w = 0; w < WIN; ++w) {
        // stage A tile: 32 rows x 300 cols of relu(gathered embedding)
        for (int i = tid; i < 32 * 300; i += 256) {
            int b = i / 300, c = i - b * 300;
            int idx = x[(b * S_LEN + t) * WIN + w];
            float v = emb[(size_t)idx * 300 + c];
            As[b][c] = v > 0.f ? v : 0.f;
        }
        __syncthreads();

        const float* Wbase = Wih1 + (size_t)w * 300;
        for (int k = 0; k < 300; k += 4) {
            float4 a[4], wv[4];
            #pragma unroll
            for (int i = 0; i < 4; ++i)
                a[i] = *(const float4*)&As[4 * bg + i][k];
            #pragma unroll
            for (int j = 0; j < 4; ++j)
                wv[j] = *(const float4*)&Wbase[woff[j] + k];
            #pragma unroll
            for (int i = 0; i < 4; ++i)
                #pragma unroll
                for (int j = 0; j < 4; ++j)
                    acc[i][j] += a[i].x * wv[j].x + a[i].y * wv[j].y
                               + a[i].z * wv[j].z + a[i].w * wv[j].w;
        }
        __syncthreads();
    }

    const int nb = n0 + 4 * ng;
    if (nb < 300) {
        float4 bi = *(const float4*)&b_ih1[nb];
        float4 bh = *(const float4*)&b_hh1[nb];
        #pragma unroll
        for (int i = 0; i < 4; ++i) {
            float4 o;
            o.x = acc[i][0] + bi.x + bh.x;
            o.y = acc[i][1] + bi.y + bh.y;
            o.z = acc[i][2] + bi.z + bh.z;
            o.w = acc[i][3] + bi.w + bh.w;
            *(float4*)&U[((size_t)(t * 32 + 4 * bg + i)) * 300 + nb] = o;
        }
    }
}

// ---------------------------------------------------------------------------
// Generic NT GEMM, K=300: C[r][n] = sum_k A[r][k]*W[n][k] + bias1[n](+bias2[n])
// grid (512, nblocks); block 256. Used for U2 (N=300, two biases).
// ---------------------------------------------------------------------------
__global__ __launch_bounds__(256) void k_gemm_nt300(
    const float* __restrict__ A, const float* __restrict__ W,
    const float* __restrict__ bias1, const float* __restrict__ bias2,
    float* __restrict__ C)
{
    const int r0  = blockIdx.x * 32;
    const int n0  = blockIdx.y * 128;
    const int tid = threadIdx.x;
    const int bg  = tid >> 5;
    const int ng  = tid & 31;

    __shared__ __align__(16) float As[32][300];
    for (int i = tid; i < 32 * 300; i += 256)
        As[i / 300][i - (i / 300) * 300] = A[(size_t)r0 * 300 + i];
    __syncthreads();

    size_t woff[4];
    #pragma unroll
    for (int j = 0; j < 4; ++j) {
        int n = n0 + 4 * ng + j;
        if (n > 299) n = 299;
        woff[j] = (size_t)n * 300;
    }

    float acc[4][4];
    #pragma unroll
    for (int i = 0; i < 4; ++i)
        #pragma unroll
        for (int j = 0; j < 4; ++j) acc[i][j] = 0.f;

    for (int k = 0; k < 300; k += 4) {
        float4 a[4], wv[4];
        #pragma unroll
        for (int i = 0; i < 4; ++i) a[i] = *(const float4*)&As[4 * bg + i][k];
        #pragma unroll
        for (int j = 0; j < 4; ++j) wv[j] = *(const float4*)&W[woff[j] + k];
        #pragma unroll
        for (int i = 0; i < 4; ++i)
            #pragma unroll
            for (int j = 0; j < 4; ++j)
                acc[i][j] += a[i].x * wv[j].x + a[i].y * wv[j].y
                           + a[i].z * wv[j].z + a[i].w * wv[j].w;
    }

    const int nb = n0 + 4 * ng;
    if (nb < 300) {
        float4 b1 = *(const float4*)&bias1[nb];
        float4 b2 = *(const float4*)&bias2[nb];
        #pragma unroll
        for (int i = 0; i < 4; ++i) {
            float4 o;
            o.x = acc[i][0] + b1.x + b2.x;
            o.y = acc[i][1] + b1.y + b2.y;
            o.z = acc[i][2] + b1.z + b2.z;
            o.w = acc[i][3] + b1.w + b2.w;
            *(float4*)&C[((size_t)(r0 + 4 * bg + i)) * 300 + nb] = o;
        }
    }
}

// ---------------------------------------------------------------------------
// FC: out[(b*512+t)*128 + n] = sum_k H[(t*32+b)*300+k]*W[n][k] + bias[n]
// grid 512 (t); block 256. N=128 exactly.
// ---------------------------------------------------------------------------
__global__ __launch_bounds__(256) void k_fc(
    const float* __restrict__ Hs, const float* __restrict__ W,
    const float* __restrict__ bias, float* __restrict__ out)
{
    const int t   = blockIdx.x;
    const int tid = threadIdx.x;
    const int bg  = tid >> 5;
    const int ng  = tid & 31;

    __shared__ __align__(16) float As[32][300];
    for (int i = tid; i < 32 * 300; i += 256)
        As[i / 300][i - (i / 300) * 300] = Hs[(size_t)t * 32 * 300 + i];
    __syncthreads();

    float acc[4][4];
    #pragma unroll
    for (int i = 0; i < 4; ++i)
        #pragma unroll
        for (int j = 0; j < 4; ++j) acc[i][j] = 0.f;

    for (int k = 0; k < 300; k += 4) {
        float4 a[4], wv[4];
        #pragma unroll
        for (int i = 0; i < 4; ++i) a[i] = *(const float4*)&As[4 * bg + i][k];
        #pragma unroll
        for (int j = 0; j < 4; ++j)
            wv[j] = *(const float4*)&W[(size_t)(4 * ng + j) * 300 + k];
        #pragma unroll
        for (int i = 0; i < 4; ++i)
            #pragma unroll
            for (int j = 0; j < 4; ++j)
                acc[i][j] += a[i].x * wv[j].x + a[i].y * wv[j].y
                           + a[i].z * wv[j].z + a[i].w * wv[j].w;
    }

    const int nb = 4 * ng;
    float4 b1 = *(const float4*)&bias[nb];
    #pragma unroll
    for (int i = 0; i < 4; ++i) {
        int b = 4 * bg + i;
        float4 o;
        o.x = acc[i][0] + b1.x;
        o.y = acc[i][1] + b1.y;
        o.z = acc[i][2] + b1.z;
        o.w = acc[i][3] + b1.w;
        *(float4*)&out[((size_t)(b * S_LEN + t)) * 128 + nb] = o;
    }
}

// ---------------------------------------------------------------------------
// Recurrence: H[t] = tanh(U[t] + W_hh @ h_{t-1}), h_0 = 0, per batch chain.
// grid 32 (one block = one chain = one CU); block 640: thread = (row, half),
// each thread holds half a W row as packed fp16 in VGPRs (75 regs),
// h broadcast via LDS fp16, v_dot2_f32_f16 accumulate in fp32.
// ---------------------------------------------------------------------------
__global__ __launch_bounds__(640) void k_rec(
    const float* __restrict__ U, const float* __restrict__ Whh,
    float* __restrict__ Hout)
{
    const int b    = blockIdx.x;
    const int tid  = threadIdx.x;
    const int row  = tid >> 1;      // 0..319
    const int half = tid & 1;
    const bool active = row < 300;

    // hs[buf][half][0..159] : each 160-half section is 320B -> 16B aligned
    __shared__ __align__(16) _Float16 hs[2][2][160];

    // load W row-half into registers as packed fp16
    hv2 wpk[75];
    if (active) {
        const float* wr = Whh + (size_t)row * 300 + half * 150;
        #pragma unroll
        for (int j = 0; j < 75; ++j) {
            hv2 p;
            p.x = (_Float16)wr[2 * j];
            p.y = (_Float16)wr[2 * j + 1];
            wpk[j] = p;
        }
    } else {
        #pragma unroll
        for (int j = 0; j < 75; ++j) { hv2 p; p.x = (_Float16)0.f; p.y = (_Float16)0.f; wpk[j] = p; }
    }

    for (int i = tid; i < 2 * 2 * 160; i += 640)
        ((_Float16*)hs)[i] = (_Float16)0.f;
    __syncthreads();

    int cur = 0;
    for (int t = 0; t < S_LEN; ++t) {
        // prefetch u early (even lanes only use it)
        float uval = 0.f;
        if (active && half == 0)
            uval = U[((size_t)(t * BATCH + b)) * 300 + row];

        const hv2* hp = (const hv2*)&hs[cur][half][0];
        float a0 = 0.f, a1 = 0.f, a2 = 0.f, a3 = 0.f, a4 = 0.f;
        #pragma unroll
        for (int j = 0; j < 15; ++j) {
            a0 = dot2f(wpk[j],      hp[j],      a0);
            a1 = dot2f(wpk[j + 15], hp[j + 15], a1);
            a2 = dot2f(wpk[j + 30], hp[j + 30], a2);
            a3 = dot2f(wpk[j + 45], hp[j + 45], a3);
            a4 = dot2f(wpk[j + 60], hp[j + 60], a4);
        }
        float acc = ((a0 + a1) + (a2 + a3)) + a4;
        float other = __shfl_xor(acc, 1);
        acc += other;

        if (active && half == 0) {
            float ht = fast_tanh(acc + uval);
            Hout[((size_t)(t * BATCH + b)) * 300 + row] = ht;
            int nb2 = cur ^ 1;
            hs[nb2][row >= 150 ? 1 : 0][row >= 150 ? row - 150 : row] = (_Float16)ht;
        }
        __syncthreads();
        cur ^= 1;
    }
}

extern "C" void kernel_launch(void* const* d_in, const int* in_sizes, int n_in,
                              void* d_out, int out_size, void* d_ws, size_t ws_size,
                              hipStream_t stream) {
    const int*   x     = (const int*)d_in[0];
    const float* emb   = (const float*)d_in[1];
    const float* Wih1  = (const float*)d_in[2];
    const float* Whh1  = (const float*)d_in[3];
    const float* bih1  = (const float*)d_in[4];
    const float* bhh1  = (const float*)d_in[5];
    const float* Wih2  = (const float*)d_in[6];
    const float* Whh2  = (const float*)d_in[7];
    const float* bih2  = (const float*)d_in[8];
    const float* bhh2  = (const float*)d_in[9];
    const float* fc1w  = (const float*)d_in[10];
    const float* fc1b  = (const float*)d_in[11];
    const float* fc2w  = (const float*)d_in[12];
    const float* fc2b  = (const float*)d_in[13];

    float* out1 = (float*)d_out;                         // [16384,128] b-major
    float* out2 = out1 + (size_t)16384 * 128;

    float* U  = (float*)d_ws;                            // [16384,300] reused for U1,U2
    float* H1 = U  + (size_t)16384 * 300;
    float* H2 = H1 + (size_t)16384 * 300;

    dim3 g3(512, 3);
    k_gemm1<<<g3, 256, 0, stream>>>(x, emb, Wih1, bih1, bhh1, U);
    k_rec<<<32, 640, 0, stream>>>(U, Whh1, H1);
    k_gemm_nt300<<<g3, 256, 0, stream>>>(H1, Wih2, bih2, bhh2, U);
    k_rec<<<32, 640, 0, stream>>>(U, Whh2, H2);
    k_fc<<<512, 256, 0, stream>>>(H1, fc1w, fc1b, out1);
    k_fc<<<512, 256, 0, stream>>>(H2, fc2w, fc2b, out2);
}

// Round 2
// 1313.912 us; speedup vs baseline: 1.5147x; 1.5147x over previous
//
#include <hip/hip_runtime.h>
#include <hip/hip_fp16.h>

#define S_LEN 512
#define BATCH 32

typedef _Float16 hv2  __attribute__((ext_vector_type(2)));
typedef _Float16 half8 __attribute__((ext_vector_type(8)));
typedef float    f32x4 __attribute__((ext_vector_type(4)));

__device__ __forceinline__ float dot2f(hv2 a, hv2 b, float c) {
#if __has_builtin(__builtin_amdgcn_fdot2)
    return __builtin_amdgcn_fdot2(a, b, c, false);
#else
    return c + (float)a.x * (float)b.x + (float)a.y * (float)b.y;
#endif
}

__device__ __forceinline__ float fast_tanh(float x) {
    float e = __expf(2.f * x);
    return 1.f - 2.f / (e + 1.f);
}

// ---------------------------------------------------------------------------
// Prep: convert to padded f16 (relu fused for emb). All pads zeroed.
//   embf [32000][320], Wf1 [320][1600] (5 windows x 320), Wf2 [320][320],
//   F1 [128][320], F2 [128][320]
// Each thread produces 8 contiguous f16 (one 16B store).
// ---------------------------------------------------------------------------
#define E8   1280000   // 32000*320/8
#define W18  64000     // 320*1600/8
#define W28  12800     // 320*320/8
#define FF8  5120      // 128*320/8
#define PREP_TOTAL8 (E8 + W18 + W28 + FF8 + FF8)

__global__ __launch_bounds__(256) void k_prep(
    const float* __restrict__ emb,  const float* __restrict__ Wih1,
    const float* __restrict__ Wih2, const float* __restrict__ fc1w,
    const float* __restrict__ fc2w,
    _Float16* __restrict__ embf, _Float16* __restrict__ Wf1,
    _Float16* __restrict__ Wf2,  _Float16* __restrict__ F1,
    _Float16* __restrict__ F2)
{
    int gid = blockIdx.x * 256 + threadIdx.x;
    if (gid >= PREP_TOTAL8) return;

    half8 v;
    _Float16* dst;

    if (gid < E8) {
        int row = gid / 40, c8 = (gid - row * 40) * 8;
        #pragma unroll
        for (int j = 0; j < 8; ++j) {
            int c = c8 + j;
            float f = (c < 300) ? emb[(size_t)row * 300 + c] : 0.f;
            v[j] = (_Float16)(f > 0.f ? f : 0.f);
        }
        dst = embf + (size_t)gid * 8;
    } else if (gid < E8 + W18) {
        int i = gid - E8;
        int row = i / 200, c8 = (i - row * 200) * 8;
        #pragma unroll
        for (int j = 0; j < 8; ++j) {
            int c = c8 + j, w = c / 320, cc = c - w * 320;
            float f = (row < 300 && cc < 300) ? Wih1[(size_t)row * 1500 + w * 300 + cc] : 0.f;
            v[j] = (_Float16)f;
        }
        dst = Wf1 + (size_t)i * 8;
    } else if (gid < E8 + W18 + W28) {
        int i = gid - E8 - W18;
        int row = i / 40, c8 = (i - row * 40) * 8;
        #pragma unroll
        for (int j = 0; j < 8; ++j) {
            int c = c8 + j;
            float f = (row < 300 && c < 300) ? Wih2[(size_t)row * 300 + c] : 0.f;
            v[j] = (_Float16)f;
        }
        dst = Wf2 + (size_t)i * 8;
    } else if (gid < E8 + W18 + W28 + FF8) {
        int i = gid - E8 - W18 - W28;
        int row = i / 40, c8 = (i - row * 40) * 8;
        #pragma unroll
        for (int j = 0; j < 8; ++j) {
            int c = c8 + j;
            v[j] = (_Float16)((c < 300) ? fc1w[(size_t)row * 300 + c] : 0.f);
        }
        dst = F1 + (size_t)i * 8;
    } else {
        int i = gid - E8 - W18 - W28 - FF8;
        int row = i / 40, c8 = (i - row * 40) * 8;
        #pragma unroll
        for (int j = 0; j < 8; ++j) {
            int c = c8 + j;
            v[j] = (_Float16)((c < 300) ? fc2w[(size_t)row * 300 + c] : 0.f);
        }
        dst = F2 + (size_t)i * 8;
    }
    *(half8*)dst = v;
}

// ---------------------------------------------------------------------------
// GEMM1 (MFMA, fused embedding gather):
//   U[r][n] = sum_{w,c} embf[x[b,t,w]][c] * Wf1[n][w*320+c] + b_ih1[n]+b_hh1[n]
//   r = t*32+b. Per-wave tile 32(M) x 160(N); block 4 waves (128x160).
//   grid (128, 2). Fragments loaded straight from global (L2/L3-resident).
// ---------------------------------------------------------------------------
__global__ __launch_bounds__(256) void k_gemm1_mfma(
    const int* __restrict__ x, const _Float16* __restrict__ embf,
    const _Float16* __restrict__ Wf1, const float* __restrict__ b1,
    const float* __restrict__ b2, float* __restrict__ U)
{
    const int wid  = threadIdx.x >> 6;
    const int lane = threadIdx.x & 63;
    const int m    = lane & 15;
    const int q    = lane >> 4;
    const int r0   = blockIdx.x * 128 + wid * 32;
    const int n0   = blockIdx.y * 160;

    f32x4 acc[2][10];
    #pragma unroll
    for (int i = 0; i < 2; ++i)
        #pragma unroll
        for (int j = 0; j < 10; ++j)
            acc[i][j] = (f32x4){0.f, 0.f, 0.f, 0.f};

    const int rA = r0 + m, rB = r0 + 16 + m;
    const int xbA = ((rA & 31) * S_LEN + (rA >> 5)) * 5;
    const int xbB = ((rB & 31) * S_LEN + (rB >> 5)) * 5;

    for (int w = 0; w < 5; ++w) {
        const int idxA = x[xbA + w];
        const int idxB = x[xbB + w];
        const _Float16* ea = embf + (size_t)idxA * 320;
        const _Float16* eb = embf + (size_t)idxB * 320;
        const _Float16* wb = Wf1 + (size_t)w * 320;
        #pragma unroll
        for (int c = 0; c < 10; ++c) {
            const int k = c * 32 + q * 8;
            half8 a0 = *(const half8*)(ea + k);
            half8 a1 = *(const half8*)(eb + k);
            #pragma unroll
            for (int nt = 0; nt < 10; ++nt) {
                half8 bf = *(const half8*)(wb + (size_t)(n0 + nt * 16 + m) * 1600 + k);
                acc[0][nt] = __builtin_amdgcn_mfma_f32_16x16x32_f16(a0, bf, acc[0][nt], 0, 0, 0);
                acc[1][nt] = __builtin_amdgcn_mfma_f32_16x16x32_f16(a1, bf, acc[1][nt], 0, 0, 0);
            }
        }
    }

    #pragma unroll
    for (int nt = 0; nt < 10; ++nt) {
        const int n = n0 + nt * 16 + m;
        if (n >= 300) continue;
        const float bias = b1[n] + b2[n];
        #pragma unroll
        for (int mt = 0; mt < 2; ++mt) {
            const int rbase = r0 + mt * 16 + q * 4;
            #pragma unroll
            for (int reg = 0; reg < 4; ++reg)
                U[(size_t)(rbase + reg) * 300 + n] = acc[mt][nt][reg] + bias;
        }
    }
}

// ---------------------------------------------------------------------------
// GEMM2 (MFMA): U[r][n] = sum_c H1f[r][c]*Wf2[n][c] + b_ih2[n]+b_hh2[n]
// Same tiling as gemm1 but K=320, A = H1 f16 [16384][320]. grid (128,2).
// ---------------------------------------------------------------------------
__global__ __launch_bounds__(256) void k_gemm2_mfma(
    const _Float16* __restrict__ H, const _Float16* __restrict__ Wf,
    const float* __restrict__ b1, const float* __restrict__ b2,
    float* __restrict__ U)
{
    const int wid  = threadIdx.x >> 6;
    const int lane = threadIdx.x & 63;
    const int m    = lane & 15;
    const int q    = lane >> 4;
    const int r0   = blockIdx.x * 128 + wid * 32;
    const int n0   = blockIdx.y * 160;

    f32x4 acc[2][10];
    #pragma unroll
    for (int i = 0; i < 2; ++i)
        #pragma unroll
        for (int j = 0; j < 10; ++j)
            acc[i][j] = (f32x4){0.f, 0.f, 0.f, 0.f};

    const _Float16* ha = H + (size_t)(r0 + m) * 320;
    const _Float16* hb = H + (size_t)(r0 + 16 + m) * 320;

    #pragma unroll
    for (int c = 0; c < 10; ++c) {
        const int k = c * 32 + q * 8;
        half8 a0 = *(const half8*)(ha + k);
        half8 a1 = *(const half8*)(hb + k);
        #pragma unroll
        for (int nt = 0; nt < 10; ++nt) {
            half8 bf = *(const half8*)(Wf + (size_t)(n0 + nt * 16 + m) * 320 + k);
            acc[0][nt] = __builtin_amdgcn_mfma_f32_16x16x32_f16(a0, bf, acc[0][nt], 0, 0, 0);
            acc[1][nt] = __builtin_amdgcn_mfma_f32_16x16x32_f16(a1, bf, acc[1][nt], 0, 0, 0);
        }
    }

    #pragma unroll
    for (int nt = 0; nt < 10; ++nt) {
        const int n = n0 + nt * 16 + m;
        if (n >= 300) continue;
        const float bias = b1[n] + b2[n];
        #pragma unroll
        for (int mt = 0; mt < 2; ++mt) {
            const int rbase = r0 + mt * 16 + q * 4;
            #pragma unroll
            for (int reg = 0; reg < 4; ++reg)
                U[(size_t)(rbase + reg) * 300 + n] = acc[mt][nt][reg] + bias;
        }
    }
}

// ---------------------------------------------------------------------------
// FC (MFMA): out[(b*512+t)*128+n] = sum_c Hf[r][c]*F[n][c] + bias[n], r=t*32+b
// Per-wave 32x128 (8 N-tiles). grid (128, 2): y = layer (H1/F1/out1 vs 2).
// ---------------------------------------------------------------------------
__global__ __launch_bounds__(256) void k_fc_mfma(
    const _Float16* __restrict__ H1, const _Float16* __restrict__ H2,
    const _Float16* __restrict__ F1, const _Float16* __restrict__ F2,
    const float* __restrict__ fb1, const float* __restrict__ fb2,
    float* __restrict__ out1, float* __restrict__ out2)
{
    const int layer = blockIdx.y;
    const _Float16* H = layer ? H2 : H1;
    const _Float16* F = layer ? F2 : F1;
    const float* bias = layer ? fb2 : fb1;
    float* out        = layer ? out2 : out1;

    const int wid  = threadIdx.x >> 6;
    const int lane = threadIdx.x & 63;
    const int m    = lane & 15;
    const int q    = lane >> 4;
    const int r0   = blockIdx.x * 128 + wid * 32;

    f32x4 acc[2][8];
    #pragma unroll
    for (int i = 0; i < 2; ++i)
        #pragma unroll
        for (int j = 0; j < 8; ++j)
            acc[i][j] = (f32x4){0.f, 0.f, 0.f, 0.f};

    const _Float16* ha = H + (size_t)(r0 + m) * 320;
    const _Float16* hb = H + (size_t)(r0 + 16 + m) * 320;

    #pragma unroll
    for (int c = 0; c < 10; ++c) {
        const int k = c * 32 + q * 8;
        half8 a0 = *(const half8*)(ha + k);
        half8 a1 = *(const half8*)(hb + k);
        #pragma unroll
        for (int nt = 0; nt < 8; ++nt) {
            half8 bf = *(const half8*)(F + (size_t)(nt * 16 + m) * 320 + k);
            acc[0][nt] = __builtin_amdgcn_mfma_f32_16x16x32_f16(a0, bf, acc[0][nt], 0, 0, 0);
            acc[1][nt] = __builtin_amdgcn_mfma_f32_16x16x32_f16(a1, bf, acc[1][nt], 0, 0, 0);
        }
    }

    #pragma unroll
    for (int nt = 0; nt < 8; ++nt) {
        const int n = nt * 16 + m;
        const float bv = bias[n];
        #pragma unroll
        for (int mt = 0; mt < 2; ++mt) {
            #pragma unroll
            for (int reg = 0; reg < 4; ++reg) {
                const int r = r0 + mt * 16 + q * 4 + reg;
                const int oidx = ((r & 31) * S_LEN + (r >> 5)) * 128 + n;
                out[oidx] = acc[mt][nt][reg] + bv;
            }
        }
    }
}

// ---------------------------------------------------------------------------
// Recurrence: H[t] = tanh(U[t] + W_hh @ h_{t-1}) per batch chain.
// grid 32; block 640 (2 threads/row); W row-halves packed f16 in VGPRs;
// h via LDS f16; v_dot2_f32_f16. Writes H as f16 padded [r][320]
// (pad cols 300..319 zeroed here). U(t+1) prefetched during step t.
// ---------------------------------------------------------------------------
__global__ __launch_bounds__(640) void k_rec(
    const float* __restrict__ U, const float* __restrict__ Whh,
    _Float16* __restrict__ Hf)
{
    const int b    = blockIdx.x;
    const int tid  = threadIdx.x;
    const int row  = tid >> 1;
    const int half = tid & 1;
    const bool active = row < 300;

    __shared__ __align__(16) _Float16 hs[2][2][160];

    hv2 wpk[75];
    if (active) {
        const float* wr = Whh + (size_t)row * 300 + half * 150;
        #pragma unroll
        for (int j = 0; j < 75; ++j) {
            hv2 p;
            p.x = (_Float16)wr[2 * j];
            p.y = (_Float16)wr[2 * j + 1];
            wpk[j] = p;
        }
    } else {
        #pragma unroll
        for (int j = 0; j < 75; ++j) { hv2 p; p.x = (_Float16)0.f; p.y = (_Float16)0.f; wpk[j] = p; }
    }

    for (int i = tid; i < 2 * 2 * 160; i += 640)
        ((_Float16*)hs)[i] = (_Float16)0.f;
    __syncthreads();

    float uval = (active && half == 0) ? U[(size_t)b * 300 + row] : 0.f;

    int cur = 0;
    for (int t = 0; t < S_LEN; ++t) {
        // prefetch next-step U early so its latency hides under this step
        float unext = 0.f;
        if (t + 1 < S_LEN && active && half == 0)
            unext = U[((size_t)((t + 1) * BATCH + b)) * 300 + row];

        const hv2* hp = (const hv2*)&hs[cur][half][0];
        float a0 = 0.f, a1 = 0.f, a2 = 0.f, a3 = 0.f, a4 = 0.f;
        #pragma unroll
        for (int j = 0; j < 15; ++j) {
            a0 = dot2f(wpk[j],      hp[j],      a0);
            a1 = dot2f(wpk[j + 15], hp[j + 15], a1);
            a2 = dot2f(wpk[j + 30], hp[j + 30], a2);
            a3 = dot2f(wpk[j + 45], hp[j + 45], a3);
            a4 = dot2f(wpk[j + 60], hp[j + 60], a4);
        }
        float acc = ((a0 + a1) + (a2 + a3)) + a4;
        acc += __shfl_xor(acc, 1);

        if (half == 0) {
            if (active) {
                float ht = fast_tanh(acc + uval);
                _Float16 hh = (_Float16)ht;
                Hf[((size_t)(t * BATCH + b)) * 320 + row] = hh;
                int nb2 = cur ^ 1;
                hs[nb2][row >= 150 ? 1 : 0][row >= 150 ? row - 150 : row] = hh;
            } else {
                // zero the f16 pad columns (rows 300..319) for MFMA consumers
                Hf[((size_t)(t * BATCH + b)) * 320 + row] = (_Float16)0.f;
            }
        }
        __syncthreads();
        uval = unext;
        cur ^= 1;
    }
}

extern "C" void kernel_launch(void* const* d_in, const int* in_sizes, int n_in,
                              void* d_out, int out_size, void* d_ws, size_t ws_size,
                              hipStream_t stream) {
    const int*   x     = (const int*)d_in[0];
    const float* emb   = (const float*)d_in[1];
    const float* Wih1  = (const float*)d_in[2];
    const float* Whh1  = (const float*)d_in[3];
    const float* bih1  = (const float*)d_in[4];
    const float* bhh1  = (const float*)d_in[5];
    const float* Wih2  = (const float*)d_in[6];
    const float* Whh2  = (const float*)d_in[7];
    const float* bih2  = (const float*)d_in[8];
    const float* bhh2  = (const float*)d_in[9];
    const float* fc1w  = (const float*)d_in[10];
    const float* fc1b  = (const float*)d_in[11];
    const float* fc2w  = (const float*)d_in[12];
    const float* fc2b  = (const float*)d_in[13];

    float* out1 = (float*)d_out;
    float* out2 = out1 + (size_t)16384 * 128;

    char* w = (char*)d_ws;
    float*    U    = (float*)w;                       // 19,660,800 B
    _Float16* H1   = (_Float16*)(w + 19660800);       // 10,485,760 B
    _Float16* Wf1  = (_Float16*)(w + 30146560);       //  1,024,000 B
    _Float16* Wf2  = (_Float16*)(w + 31170560);       //    204,800 B
    _Float16* F1   = (_Float16*)(w + 31375360);       //     81,920 B
    _Float16* F2   = (_Float16*)(w + 31457280);       //     81,920 B
    _Float16* EMBF = (_Float16*)(w + 31539200);       // 20,480,000 B
    _Float16* H2   = EMBF;  // reuse: gemm1 is done with EMBF before rec2 writes H2

    const int prep_blocks = (PREP_TOTAL8 + 255) / 256;
    k_prep<<<prep_blocks, 256, 0, stream>>>(emb, Wih1, Wih2, fc1w, fc2w,
                                            EMBF, Wf1, Wf2, F1, F2);

    dim3 g(128, 2);
    k_gemm1_mfma<<<g, 256, 0, stream>>>(x, EMBF, Wf1, bih1, bhh1, U);
    k_rec<<<32, 640, 0, stream>>>(U, Whh1, H1);
    k_gemm2_mfma<<<g, 256, 0, stream>>>(H1, Wf2, bih2, bhh2, U);
    k_rec<<<32, 640, 0, stream>>>(U, Whh2, H2);
    k_fc_mfma<<<g, 256, 0, stream>>>(H1, H2, F1, F2, fc1b, fc2b, out1, out2);
}

// Round 3
// 1238.416 us; speedup vs baseline: 1.6071x; 1.0610x over previous
//
#include <hip/hip_runtime.h>
#include <hip/hip_fp16.h>

#define S_LEN 512
#define BATCH 32

typedef _Float16 hv2  __attribute__((ext_vector_type(2)));
typedef _Float16 half8 __attribute__((ext_vector_type(8)));
typedef float    f32x4 __attribute__((ext_vector_type(4)));

__device__ __forceinline__ float dot2f(hv2 a, hv2 b, float c) {
#if __has_builtin(__builtin_amdgcn_fdot2)
    return __builtin_amdgcn_fdot2(a, b, c, false);
#else
    return c + (float)a.x * (float)b.x + (float)a.y * (float)b.y;
#endif
}

__device__ __forceinline__ float fast_tanh(float x) {
    float e = __expf(2.f * x);
    return 1.f - 2.f / (e + 1.f);
}

// ---------------------------------------------------------------------------
// Prep: convert to padded f16 (relu fused for emb). All pads zeroed.
// ---------------------------------------------------------------------------
#define E8   1280000   // 32000*320/8
#define W18  64000     // 320*1600/8
#define W28  12800     // 320*320/8
#define FF8  5120      // 128*320/8
#define PREP_TOTAL8 (E8 + W18 + W28 + FF8 + FF8)

__global__ __launch_bounds__(256) void k_prep(
    const float* __restrict__ emb,  const float* __restrict__ Wih1,
    const float* __restrict__ Wih2, const float* __restrict__ fc1w,
    const float* __restrict__ fc2w,
    _Float16* __restrict__ embf, _Float16* __restrict__ Wf1,
    _Float16* __restrict__ Wf2,  _Float16* __restrict__ F1,
    _Float16* __restrict__ F2)
{
    int gid = blockIdx.x * 256 + threadIdx.x;
    if (gid >= PREP_TOTAL8) return;

    half8 v;
    _Float16* dst;

    if (gid < E8) {
        int row = gid / 40, c8 = (gid - row * 40) * 8;
        #pragma unroll
        for (int j = 0; j < 8; ++j) {
            int c = c8 + j;
            float f = (c < 300) ? emb[(size_t)row * 300 + c] : 0.f;
            v[j] = (_Float16)(f > 0.f ? f : 0.f);
        }
        dst = embf + (size_t)gid * 8;
    } else if (gid < E8 + W18) {
        int i = gid - E8;
        int row = i / 200, c8 = (i - row * 200) * 8;
        #pragma unroll
        for (int j = 0; j < 8; ++j) {
            int c = c8 + j, w = c / 320, cc = c - w * 320;
            float f = (row < 300 && cc < 300) ? Wih1[(size_t)row * 1500 + w * 300 + cc] : 0.f;
            v[j] = (_Float16)f;
        }
        dst = Wf1 + (size_t)i * 8;
    } else if (gid < E8 + W18 + W28) {
        int i = gid - E8 - W18;
        int row = i / 40, c8 = (i - row * 40) * 8;
        #pragma unroll
        for (int j = 0; j < 8; ++j) {
            int c = c8 + j;
            float f = (row < 300 && c < 300) ? Wih2[(size_t)row * 300 + c] : 0.f;
            v[j] = (_Float16)f;
        }
        dst = Wf2 + (size_t)i * 8;
    } else if (gid < E8 + W18 + W28 + FF8) {
        int i = gid - E8 - W18 - W28;
        int row = i / 40, c8 = (i - row * 40) * 8;
        #pragma unroll
        for (int j = 0; j < 8; ++j) {
            int c = c8 + j;
            v[j] = (_Float16)((c < 300) ? fc1w[(size_t)row * 300 + c] : 0.f);
        }
        dst = F1 + (size_t)i * 8;
    } else {
        int i = gid - E8 - W18 - W28 - FF8;
        int row = i / 40, c8 = (i - row * 40) * 8;
        #pragma unroll
        for (int j = 0; j < 8; ++j) {
            int c = c8 + j;
            v[j] = (_Float16)((c < 300) ? fc2w[(size_t)row * 300 + c] : 0.f);
        }
        dst = F2 + (size_t)i * 8;
    }
    *(half8*)dst = v;
}

// ---------------------------------------------------------------------------
// GEMM1 (MFMA, fused embedding gather). grid (128,2), block 256.
// ---------------------------------------------------------------------------
__global__ __launch_bounds__(256) void k_gemm1_mfma(
    const int* __restrict__ x, const _Float16* __restrict__ embf,
    const _Float16* __restrict__ Wf1, const float* __restrict__ b1,
    const float* __restrict__ b2, float* __restrict__ U)
{
    const int wid  = threadIdx.x >> 6;
    const int lane = threadIdx.x & 63;
    const int m    = lane & 15;
    const int q    = lane >> 4;
    const int r0   = blockIdx.x * 128 + wid * 32;
    const int n0   = blockIdx.y * 160;

    f32x4 acc[2][10];
    #pragma unroll
    for (int i = 0; i < 2; ++i)
        #pragma unroll
        for (int j = 0; j < 10; ++j)
            acc[i][j] = (f32x4){0.f, 0.f, 0.f, 0.f};

    const int rA = r0 + m, rB = r0 + 16 + m;
    const int xbA = ((rA & 31) * S_LEN + (rA >> 5)) * 5;
    const int xbB = ((rB & 31) * S_LEN + (rB >> 5)) * 5;

    for (int w = 0; w < 5; ++w) {
        const int idxA = x[xbA + w];
        const int idxB = x[xbB + w];
        const _Float16* ea = embf + (size_t)idxA * 320;
        const _Float16* eb = embf + (size_t)idxB * 320;
        const _Float16* wb = Wf1 + (size_t)w * 320;
        #pragma unroll
        for (int c = 0; c < 10; ++c) {
            const int k = c * 32 + q * 8;
            half8 a0 = *(const half8*)(ea + k);
            half8 a1 = *(const half8*)(eb + k);
            #pragma unroll
            for (int nt = 0; nt < 10; ++nt) {
                half8 bf = *(const half8*)(wb + (size_t)(n0 + nt * 16 + m) * 1600 + k);
                acc[0][nt] = __builtin_amdgcn_mfma_f32_16x16x32_f16(a0, bf, acc[0][nt], 0, 0, 0);
                acc[1][nt] = __builtin_amdgcn_mfma_f32_16x16x32_f16(a1, bf, acc[1][nt], 0, 0, 0);
            }
        }
    }

    #pragma unroll
    for (int nt = 0; nt < 10; ++nt) {
        const int n = n0 + nt * 16 + m;
        if (n >= 300) continue;
        const float bias = b1[n] + b2[n];
        #pragma unroll
        for (int mt = 0; mt < 2; ++mt) {
            const int rbase = r0 + mt * 16 + q * 4;
            #pragma unroll
            for (int reg = 0; reg < 4; ++reg)
                U[(size_t)(rbase + reg) * 300 + n] = acc[mt][nt][reg] + bias;
        }
    }
}

// ---------------------------------------------------------------------------
// GEMM2 (MFMA): K=320, A = H f16 [16384][320]. grid (128,2), block 256.
// ---------------------------------------------------------------------------
__global__ __launch_bounds__(256) void k_gemm2_mfma(
    const _Float16* __restrict__ H, const _Float16* __restrict__ Wf,
    const float* __restrict__ b1, const float* __restrict__ b2,
    float* __restrict__ U)
{
    const int wid  = threadIdx.x >> 6;
    const int lane = threadIdx.x & 63;
    const int m    = lane & 15;
    const int q    = lane >> 4;
    const int r0   = blockIdx.x * 128 + wid * 32;
    const int n0   = blockIdx.y * 160;

    f32x4 acc[2][10];
    #pragma unroll
    for (int i = 0; i < 2; ++i)
        #pragma unroll
        for (int j = 0; j < 10; ++j)
            acc[i][j] = (f32x4){0.f, 0.f, 0.f, 0.f};

    const _Float16* ha = H + (size_t)(r0 + m) * 320;
    const _Float16* hb = H + (size_t)(r0 + 16 + m) * 320;

    #pragma unroll
    for (int c = 0; c < 10; ++c) {
        const int k = c * 32 + q * 8;
        half8 a0 = *(const half8*)(ha + k);
        half8 a1 = *(const half8*)(hb + k);
        #pragma unroll
        for (int nt = 0; nt < 10; ++nt) {
            half8 bf = *(const half8*)(Wf + (size_t)(n0 + nt * 16 + m) * 320 + k);
            acc[0][nt] = __builtin_amdgcn_mfma_f32_16x16x32_f16(a0, bf, acc[0][nt], 0, 0, 0);
            acc[1][nt] = __builtin_amdgcn_mfma_f32_16x16x32_f16(a1, bf, acc[1][nt], 0, 0, 0);
        }
    }

    #pragma unroll
    for (int nt = 0; nt < 10; ++nt) {
        const int n = n0 + nt * 16 + m;
        if (n >= 300) continue;
        const float bias = b1[n] + b2[n];
        #pragma unroll
        for (int mt = 0; mt < 2; ++mt) {
            const int rbase = r0 + mt * 16 + q * 4;
            #pragma unroll
            for (int reg = 0; reg < 4; ++reg)
                U[(size_t)(rbase + reg) * 300 + n] = acc[mt][nt][reg] + bias;
        }
    }
}

// ---------------------------------------------------------------------------
// FC (MFMA): per-wave 32x128. grid (128, 2): y = layer.
// ---------------------------------------------------------------------------
__global__ __launch_bounds__(256) void k_fc_mfma(
    const _Float16* __restrict__ H1, const _Float16* __restrict__ H2,
    const _Float16* __restrict__ F1, const _Float16* __restrict__ F2,
    const float* __restrict__ fb1, const float* __restrict__ fb2,
    float* __restrict__ out1, float* __restrict__ out2)
{
    const int layer = blockIdx.y;
    const _Float16* H = layer ? H2 : H1;
    const _Float16* F = layer ? F2 : F1;
    const float* bias = layer ? fb2 : fb1;
    float* out        = layer ? out2 : out1;

    const int wid  = threadIdx.x >> 6;
    const int lane = threadIdx.x & 63;
    const int m    = lane & 15;
    const int q    = lane >> 4;
    const int r0   = blockIdx.x * 128 + wid * 32;

    f32x4 acc[2][8];
    #pragma unroll
    for (int i = 0; i < 2; ++i)
        #pragma unroll
        for (int j = 0; j < 8; ++j)
            acc[i][j] = (f32x4){0.f, 0.f, 0.f, 0.f};

    const _Float16* ha = H + (size_t)(r0 + m) * 320;
    const _Float16* hb = H + (size_t)(r0 + 16 + m) * 320;

    #pragma unroll
    for (int c = 0; c < 10; ++c) {
        const int k = c * 32 + q * 8;
        half8 a0 = *(const half8*)(ha + k);
        half8 a1 = *(const half8*)(hb + k);
        #pragma unroll
        for (int nt = 0; nt < 8; ++nt) {
            half8 bf = *(const half8*)(F + (size_t)(nt * 16 + m) * 320 + k);
            acc[0][nt] = __builtin_amdgcn_mfma_f32_16x16x32_f16(a0, bf, acc[0][nt], 0, 0, 0);
            acc[1][nt] = __builtin_amdgcn_mfma_f32_16x16x32_f16(a1, bf, acc[1][nt], 0, 0, 0);
        }
    }

    #pragma unroll
    for (int nt = 0; nt < 8; ++nt) {
        const int n = nt * 16 + m;
        const float bv = bias[n];
        #pragma unroll
        for (int mt = 0; mt < 2; ++mt) {
            #pragma unroll
            for (int reg = 0; reg < 4; ++reg) {
                const int r = r0 + mt * 16 + q * 4 + reg;
                const int oidx = ((r & 31) * S_LEN + (r >> 5)) * 128 + n;
                out[oidx] = acc[mt][nt][reg] + bv;
            }
        }
    }
}

// ---------------------------------------------------------------------------
// Recurrence v2: H[t] = tanh(U[t] + W_hh @ h_{t-1}) per batch chain.
// grid 32, block 640 (600 active compute threads).
// 2-D tiling: thread (g = tid/60, rt = tid%60) computes rows {rt+60i, i<5}
// x cols [32g, 32g+32) with W register-resident f16 (80 VGPRs/thread).
// Per step: 4x ds_read_b128 of h-segment (broadcast) -> 80 dot2 -> 5 fp32
// partials to LDS -> barrier -> 300 threads reduce 10 partials + tanh ->
// h to LDS f16 + global Hf (padded [.][320]) -> barrier.
// LDS delivery/step: ~36KB h + 12KB partials + 12KB reduce (vs 192KB in v1).
// ---------------------------------------------------------------------------
__global__ __launch_bounds__(640) void k_rec(
    const float* __restrict__ U, const float* __restrict__ Whh,
    _Float16* __restrict__ Hf)
{
    const int b   = blockIdx.x;
    const int tid = threadIdx.x;
    const int g   = tid / 60;    // 0..9 (col group) for tid<600
    const int rt  = tid % 60;    // row-tile base; rows rt+60i
    const bool comp = tid < 600;

    __shared__ __align__(16) _Float16 hbuf[2][320];
    __shared__ float partials[10][304];

    // preload W tile: rows rt+60i, cols 32g..32g+31, as packed f16
    hv2 w[5][16];
    if (comp) {
        #pragma unroll
        for (int i = 0; i < 5; ++i) {
            const float* wr = Whh + (size_t)(rt + 60 * i) * 300 + g * 32;
            #pragma unroll
            for (int j = 0; j < 16; ++j) {
                int c0 = g * 32 + 2 * j;
                hv2 p;
                p.x = (c0     < 300) ? (_Float16)wr[2 * j]     : (_Float16)0.f;
                p.y = (c0 + 1 < 300) ? (_Float16)wr[2 * j + 1] : (_Float16)0.f;
                w[i][j] = p;
            }
        }
    } else {
        #pragma unroll
        for (int i = 0; i < 5; ++i)
            #pragma unroll
            for (int j = 0; j < 16; ++j) { hv2 p; p.x = (_Float16)0.f; p.y = (_Float16)0.f; w[i][j] = p; }
    }

    // zero both h buffers (incl. pad cols 300..319, which stay 0 forever)
    for (int i = tid; i < 2 * 320; i += 640)
        ((_Float16*)hbuf)[i] = (_Float16)0.f;
    __syncthreads();

    float uval = (tid < 300) ? U[(size_t)b * 300 + tid] : 0.f;

    int cur = 0;
    for (int t = 0; t < S_LEN; ++t) {
        if (comp) {
            const half8* hp8 = (const half8*)&hbuf[cur][g * 32];
            hv2 hh[16];
            *(half8*)&hh[0]  = hp8[0];
            *(half8*)&hh[4]  = hp8[1];
            *(half8*)&hh[8]  = hp8[2];
            *(half8*)&hh[12] = hp8[3];

            float a0 = 0.f, a1 = 0.f, a2 = 0.f, a3 = 0.f, a4 = 0.f;
            #pragma unroll
            for (int j = 0; j < 16; ++j) {
                a0 = dot2f(w[0][j], hh[j], a0);
                a1 = dot2f(w[1][j], hh[j], a1);
                a2 = dot2f(w[2][j], hh[j], a2);
                a3 = dot2f(w[3][j], hh[j], a3);
                a4 = dot2f(w[4][j], hh[j], a4);
            }
            partials[g][rt]       = a0;
            partials[g][rt + 60]  = a1;
            partials[g][rt + 120] = a2;
            partials[g][rt + 180] = a3;
            partials[g][rt + 240] = a4;
        }
        __syncthreads();

        float unext = 0.f;
        if (tid < 300) {
            if (t + 1 < S_LEN)
                unext = U[((size_t)((t + 1) * BATCH + b)) * 300 + tid];
            float s = uval;
            #pragma unroll
            for (int g2 = 0; g2 < 10; ++g2)
                s += partials[g2][tid];
            float ht = fast_tanh(s);
            _Float16 hf = (_Float16)ht;
            hbuf[cur ^ 1][tid] = hf;
            Hf[((size_t)(t * BATCH + b)) * 320 + tid] = hf;
        } else if (tid < 320) {
            Hf[((size_t)(t * BATCH + b)) * 320 + tid] = (_Float16)0.f;
        }
        __syncthreads();
        uval = unext;
        cur ^= 1;
    }
}

extern "C" void kernel_launch(void* const* d_in, const int* in_sizes, int n_in,
                              void* d_out, int out_size, void* d_ws, size_t ws_size,
                              hipStream_t stream) {
    const int*   x     = (const int*)d_in[0];
    const float* emb   = (const float*)d_in[1];
    const float* Wih1  = (const float*)d_in[2];
    const float* Whh1  = (const float*)d_in[3];
    const float* bih1  = (const float*)d_in[4];
    const float* bhh1  = (const float*)d_in[5];
    const float* Wih2  = (const float*)d_in[6];
    const float* Whh2  = (const float*)d_in[7];
    const float* bih2  = (const float*)d_in[8];
    const float* bhh2  = (const float*)d_in[9];
    const float* fc1w  = (const float*)d_in[10];
    const float* fc1b  = (const float*)d_in[11];
    const float* fc2w  = (const float*)d_in[12];
    const float* fc2b  = (const float*)d_in[13];

    float* out1 = (float*)d_out;
    float* out2 = out1 + (size_t)16384 * 128;

    char* w = (char*)d_ws;
    float*    U    = (float*)w;                       // 19,660,800 B
    _Float16* H1   = (_Float16*)(w + 19660800);       // 10,485,760 B
    _Float16* Wf1  = (_Float16*)(w + 30146560);       //  1,024,000 B
    _Float16* Wf2  = (_Float16*)(w + 31170560);       //    204,800 B
    _Float16* F1   = (_Float16*)(w + 31375360);       //     81,920 B
    _Float16* F2   = (_Float16*)(w + 31457280);       //     81,920 B
    _Float16* EMBF = (_Float16*)(w + 31539200);       // 20,480,000 B
    _Float16* H2   = EMBF;  // reuse: gemm1 done with EMBF before rec2 writes H2

    const int prep_blocks = (PREP_TOTAL8 + 255) / 256;
    k_prep<<<prep_blocks, 256, 0, stream>>>(emb, Wih1, Wih2, fc1w, fc2w,
                                            EMBF, Wf1, Wf2, F1, F2);

    dim3 g(128, 2);
    k_gemm1_mfma<<<g, 256, 0, stream>>>(x, EMBF, Wf1, bih1, bhh1, U);
    k_rec<<<32, 640, 0, stream>>>(U, Whh1, H1);
    k_gemm2_mfma<<<g, 256, 0, stream>>>(H1, Wf2, bih2, bhh2, U);
    k_rec<<<32, 640, 0, stream>>>(U, Whh2, H2);
    k_fc_mfma<<<g, 256, 0, stream>>>(H1, H2, F1, F2, fc1b, fc2b, out1, out2);
}

// Round 4
// 907.791 us; speedup vs baseline: 2.1924x; 1.3642x over previous
//
#include <hip/hip_runtime.h>
#include <hip/hip_fp16.h>

#define S_LEN 512
#define BATCH 32
#define CHUNK 16

typedef _Float16 hv2  __attribute__((ext_vector_type(2)));
typedef _Float16 half8 __attribute__((ext_vector_type(8)));
typedef float    f32x4 __attribute__((ext_vector_type(4)));

__device__ __forceinline__ float dot2f(hv2 a, hv2 b, float c) {
#if __has_builtin(__builtin_amdgcn_fdot2)
    return __builtin_amdgcn_fdot2(a, b, c, false);
#else
    return c + (float)a.x * (float)b.x + (float)a.y * (float)b.y;
#endif
}

__device__ __forceinline__ float fast_tanh(float x) {
    float e = __expf(2.f * x);
    return 1.f - 2.f / (e + 1.f);
}

// ---------------------------------------------------------------------------
// Prep: convert to padded f16 (relu fused for emb). Also zeroes the
// producer->consumer flags (ws is poisoned 0xAA before every timed launch).
// ---------------------------------------------------------------------------
#define E8   1280000   // 32000*320/8
#define W18  64000     // 320*1600/8
#define FF8  5120      // 128*320/8
#define PREP_TOTAL8 (E8 + W18 + FF8 + FF8)

__global__ __launch_bounds__(256) void k_prep(
    const float* __restrict__ emb,  const float* __restrict__ Wih1,
    const float* __restrict__ fc1w, const float* __restrict__ fc2w,
    _Float16* __restrict__ embf, _Float16* __restrict__ Wf1,
    _Float16* __restrict__ F1,   _Float16* __restrict__ F2,
    unsigned int* __restrict__ flags)
{
    int gid = blockIdx.x * 256 + threadIdx.x;
    if (gid < 64) flags[gid] = 0u;
    if (gid >= PREP_TOTAL8) return;

    half8 v;
    _Float16* dst;

    if (gid < E8) {
        int row = gid / 40, c8 = (gid - row * 40) * 8;
        #pragma unroll
        for (int j = 0; j < 8; ++j) {
            int c = c8 + j;
            float f = (c < 300) ? emb[(size_t)row * 300 + c] : 0.f;
            v[j] = (_Float16)(f > 0.f ? f : 0.f);
        }
        dst = embf + (size_t)gid * 8;
    } else if (gid < E8 + W18) {
        int i = gid - E8;
        int row = i / 200, c8 = (i - row * 200) * 8;
        #pragma unroll
        for (int j = 0; j < 8; ++j) {
            int c = c8 + j, w = c / 320, cc = c - w * 320;
            float f = (row < 300 && cc < 300) ? Wih1[(size_t)row * 1500 + w * 300 + cc] : 0.f;
            v[j] = (_Float16)f;
        }
        dst = Wf1 + (size_t)i * 8;
    } else if (gid < E8 + W18 + FF8) {
        int i = gid - E8 - W18;
        int row = i / 40, c8 = (i - row * 40) * 8;
        #pragma unroll
        for (int j = 0; j < 8; ++j) {
            int c = c8 + j;
            v[j] = (_Float16)((c < 300) ? fc1w[(size_t)row * 300 + c] : 0.f);
        }
        dst = F1 + (size_t)i * 8;
    } else {
        int i = gid - E8 - W18 - FF8;
        int row = i / 40, c8 = (i - row * 40) * 8;
        #pragma unroll
        for (int j = 0; j < 8; ++j) {
            int c = c8 + j;
            v[j] = (_Float16)((c < 300) ? fc2w[(size_t)row * 300 + c] : 0.f);
        }
        dst = F2 + (size_t)i * 8;
    }
    *(half8*)dst = v;
}

// ---------------------------------------------------------------------------
// GEMM1 (MFMA, fused embedding gather). grid (128,2), block 256.
// ---------------------------------------------------------------------------
__global__ __launch_bounds__(256) void k_gemm1_mfma(
    const int* __restrict__ x, const _Float16* __restrict__ embf,
    const _Float16* __restrict__ Wf1, const float* __restrict__ b1,
    const float* __restrict__ b2, float* __restrict__ U)
{
    const int wid  = threadIdx.x >> 6;
    const int lane = threadIdx.x & 63;
    const int m    = lane & 15;
    const int q    = lane >> 4;
    const int r0   = blockIdx.x * 128 + wid * 32;
    const int n0   = blockIdx.y * 160;

    f32x4 acc[2][10];
    #pragma unroll
    for (int i = 0; i < 2; ++i)
        #pragma unroll
        for (int j = 0; j < 10; ++j)
            acc[i][j] = (f32x4){0.f, 0.f, 0.f, 0.f};

    const int rA = r0 + m, rB = r0 + 16 + m;
    const int xbA = ((rA & 31) * S_LEN + (rA >> 5)) * 5;
    const int xbB = ((rB & 31) * S_LEN + (rB >> 5)) * 5;

    for (int w = 0; w < 5; ++w) {
        const int idxA = x[xbA + w];
        const int idxB = x[xbB + w];
        const _Float16* ea = embf + (size_t)idxA * 320;
        const _Float16* eb = embf + (size_t)idxB * 320;
        const _Float16* wb = Wf1 + (size_t)w * 320;
        #pragma unroll
        for (int c = 0; c < 10; ++c) {
            const int k = c * 32 + q * 8;
            half8 a0 = *(const half8*)(ea + k);
            half8 a1 = *(const half8*)(eb + k);
            #pragma unroll
            for (int nt = 0; nt < 10; ++nt) {
                half8 bf = *(const half8*)(wb + (size_t)(n0 + nt * 16 + m) * 1600 + k);
                acc[0][nt] = __builtin_amdgcn_mfma_f32_16x16x32_f16(a0, bf, acc[0][nt], 0, 0, 0);
                acc[1][nt] = __builtin_amdgcn_mfma_f32_16x16x32_f16(a1, bf, acc[1][nt], 0, 0, 0);
            }
        }
    }

    #pragma unroll
    for (int nt = 0; nt < 10; ++nt) {
        const int n = n0 + nt * 16 + m;
        if (n >= 300) continue;
        const float bias = b1[n] + b2[n];
        #pragma unroll
        for (int mt = 0; mt < 2; ++mt) {
            const int rbase = r0 + mt * 16 + q * 4;
            #pragma unroll
            for (int reg = 0; reg < 4; ++reg)
                U[(size_t)(rbase + reg) * 300 + n] = acc[mt][nt][reg] + bias;
        }
    }
}

// ---------------------------------------------------------------------------
// FC (MFMA): per-wave 32x128. grid (128, 2): y = layer.
// ---------------------------------------------------------------------------
__global__ __launch_bounds__(256) void k_fc_mfma(
    const _Float16* __restrict__ H1, const _Float16* __restrict__ H2,
    const _Float16* __restrict__ F1, const _Float16* __restrict__ F2,
    const float* __restrict__ fb1, const float* __restrict__ fb2,
    float* __restrict__ out1, float* __restrict__ out2)
{
    const int layer = blockIdx.y;
    const _Float16* H = layer ? H2 : H1;
    const _Float16* F = layer ? F2 : F1;
    const float* bias = layer ? fb2 : fb1;
    float* out        = layer ? out2 : out1;

    const int wid  = threadIdx.x >> 6;
    const int lane = threadIdx.x & 63;
    const int m    = lane & 15;
    const int q    = lane >> 4;
    const int r0   = blockIdx.x * 128 + wid * 32;

    f32x4 acc[2][8];
    #pragma unroll
    for (int i = 0; i < 2; ++i)
        #pragma unroll
        for (int j = 0; j < 8; ++j)
            acc[i][j] = (f32x4){0.f, 0.f, 0.f, 0.f};

    const _Float16* ha = H + (size_t)(r0 + m) * 320;
    const _Float16* hb = H + (size_t)(r0 + 16 + m) * 320;

    #pragma unroll
    for (int c = 0; c < 10; ++c) {
        const int k = c * 32 + q * 8;
        half8 a0 = *(const half8*)(ha + k);
        half8 a1 = *(const half8*)(hb + k);
        #pragma unroll
        for (int nt = 0; nt < 8; ++nt) {
            half8 bf = *(const half8*)(F + (size_t)(nt * 16 + m) * 320 + k);
            acc[0][nt] = __builtin_amdgcn_mfma_f32_16x16x32_f16(a0, bf, acc[0][nt], 0, 0, 0);
            acc[1][nt] = __builtin_amdgcn_mfma_f32_16x16x32_f16(a1, bf, acc[1][nt], 0, 0, 0);
        }
    }

    #pragma unroll
    for (int nt = 0; nt < 8; ++nt) {
        const int n = nt * 16 + m;
        const float bv = bias[n];
        #pragma unroll
        for (int mt = 0; mt < 2; ++mt) {
            #pragma unroll
            for (int reg = 0; reg < 4; ++reg) {
                const int r = r0 + mt * 16 + q * 4 + reg;
                const int oidx = ((r & 31) * S_LEN + (r >> 5)) * 128 + n;
                out[oidx] = acc[mt][nt][reg] + bv;
            }
        }
    }
}

// ---------------------------------------------------------------------------
// Fused recurrence: 64 blocks x 512 threads.
//   blocks 0..31  (producer): chain b, h1_t = tanh(U1_t + Whh1 h1_{t-1});
//       writes H1 (f16, padded 320), publishes a release-flag every CHUNK steps.
//   blocks 32..63 (consumer): chain b, h2_t = tanh(bih2+bhh2 + Wih2 h1_t
//       + Whh2 h2_{t-1}); acquires flag, stages H1 chunk to LDS, two fused
//       matvecs per step. Absorbs the old gemm2.
// Compute tiling (both): 500 threads = 10 col-groups(32) x 50 row-threads,
// 6 rows each; W register-resident f16 (96 VGPR per matrix).
// ---------------------------------------------------------------------------
__global__ __launch_bounds__(512, 2) void k_rec_fused(
    const float* __restrict__ U1, const float* __restrict__ Whh1,
    const float* __restrict__ Wih2, const float* __restrict__ Whh2,
    const float* __restrict__ bih2, const float* __restrict__ bhh2,
    _Float16* __restrict__ H1f, _Float16* __restrict__ H2f,
    unsigned int* __restrict__ flags)
{
    const int tid  = threadIdx.x;
    const bool comp = tid < 500;
    const int g    = comp ? tid / 50 : 0;    // 0..9 col group (32 cols)
    const int rt   = comp ? tid % 50 : 0;    // rows rt + 50i, i<6

    __shared__ __align__(16) _Float16 hbuf[2][320];
    __shared__ float partials[10][304];
    __shared__ __align__(16) _Float16 h1c[CHUNK][320];

    for (int i = tid; i < 2 * 320; i += 512)
        ((_Float16*)hbuf)[i] = (_Float16)0.f;

    if (blockIdx.x < 32) {
        // ================= producer: layer 1 =================
        const int b = blockIdx.x;
        hv2 w1[6][16];
        if (comp) {
            #pragma unroll
            for (int i = 0; i < 6; ++i) {
                const float* wr = Whh1 + (size_t)(rt + 50 * i) * 300 + g * 32;
                #pragma unroll
                for (int j = 0; j < 16; ++j) {
                    int c0 = g * 32 + 2 * j;
                    hv2 p;
                    p.x = (c0     < 300) ? (_Float16)wr[2 * j]     : (_Float16)0.f;
                    p.y = (c0 + 1 < 300) ? (_Float16)wr[2 * j + 1] : (_Float16)0.f;
                    w1[i][j] = p;
                }
            }
        }
        __syncthreads();

        float uval = (tid < 300) ? U1[(size_t)b * 300 + tid] : 0.f;

        int cur = 0;
        for (int t = 0; t < S_LEN; ++t) {
            float unext = 0.f;
            if (tid < 300 && t + 1 < S_LEN)
                unext = U1[((size_t)((t + 1) * BATCH + b)) * 300 + tid];

            if (comp) {
                const half8* hp = (const half8*)&hbuf[cur][g * 32];
                float a0 = 0.f, a1 = 0.f, a2 = 0.f, a3 = 0.f, a4 = 0.f, a5 = 0.f;
                #pragma unroll
                for (int jj = 0; jj < 4; ++jj) {
                    half8 q = hp[jj];
                    const hv2* qv = (const hv2*)&q;
                    #pragma unroll
                    for (int j4 = 0; j4 < 4; ++j4) {
                        const int j = 4 * jj + j4;
                        a0 = dot2f(w1[0][j], qv[j4], a0);
                        a1 = dot2f(w1[1][j], qv[j4], a1);
                        a2 = dot2f(w1[2][j], qv[j4], a2);
                        a3 = dot2f(w1[3][j], qv[j4], a3);
                        a4 = dot2f(w1[4][j], qv[j4], a4);
                        a5 = dot2f(w1[5][j], qv[j4], a5);
                    }
                }
                partials[g][rt]       = a0;
                partials[g][rt + 50]  = a1;
                partials[g][rt + 100] = a2;
                partials[g][rt + 150] = a3;
                partials[g][rt + 200] = a4;
                partials[g][rt + 250] = a5;
            }
            __syncthreads();

            if (tid < 300) {
                float s = uval;
                #pragma unroll
                for (int g2 = 0; g2 < 10; ++g2)
                    s += partials[g2][tid];
                float ht = fast_tanh(s);
                _Float16 hf = (_Float16)ht;
                hbuf[cur ^ 1][tid] = hf;
                H1f[((size_t)(t * BATCH + b)) * 320 + tid] = hf;
            } else if (tid < 320) {
                H1f[((size_t)(t * BATCH + b)) * 320 + tid] = (_Float16)0.f;
            }
            __syncthreads();

            if (((t + 1) & (CHUNK - 1)) == 0 && tid == 0) {
                // all this chunk's H1 stores drained to L2 at the barrier;
                // agent-release writes back L2 so consumer XCDs see them.
                __hip_atomic_store(&flags[b], (unsigned)(t + 1),
                                   __ATOMIC_RELEASE, __HIP_MEMORY_SCOPE_AGENT);
            }
            uval = unext;
            cur ^= 1;
        }
    } else {
        // ================= consumer: layer 2 =================
        const int b = blockIdx.x - 32;
        hv2 wih[6][16], whh[6][16];
        if (comp) {
            #pragma unroll
            for (int i = 0; i < 6; ++i) {
                const float* wr = Wih2 + (size_t)(rt + 50 * i) * 300 + g * 32;
                const float* wr2 = Whh2 + (size_t)(rt + 50 * i) * 300 + g * 32;
                #pragma unroll
                for (int j = 0; j < 16; ++j) {
                    int c0 = g * 32 + 2 * j;
                    hv2 p, p2;
                    p.x  = (c0     < 300) ? (_Float16)wr[2 * j]      : (_Float16)0.f;
                    p.y  = (c0 + 1 < 300) ? (_Float16)wr[2 * j + 1]  : (_Float16)0.f;
                    p2.x = (c0     < 300) ? (_Float16)wr2[2 * j]     : (_Float16)0.f;
                    p2.y = (c0 + 1 < 300) ? (_Float16)wr2[2 * j + 1] : (_Float16)0.f;
                    wih[i][j] = p;
                    whh[i][j] = p2;
                }
            }
        }
        float bias = 0.f;
        if (tid < 300) bias = bih2[tid] + bhh2[tid];
        __syncthreads();

        int cur = 0;
        for (int t = 0; t < S_LEN; ++t) {
            if ((t & (CHUNK - 1)) == 0) {
                if (tid == 0) {
                    while (__hip_atomic_load(&flags[b], __ATOMIC_ACQUIRE,
                                             __HIP_MEMORY_SCOPE_AGENT) < (unsigned)(t + CHUNK))
                        __builtin_amdgcn_s_sleep(8);
                }
                __syncthreads();
                for (int idx = tid; idx < CHUNK * 40; idx += 512) {
                    int row = idx / 40, o8 = idx - row * 40;
                    *(half8*)&h1c[row][o8 * 8] =
                        *(const half8*)&H1f[((size_t)((t + row) * BATCH + b)) * 320 + o8 * 8];
                }
                __syncthreads();
            }

            if (comp) {
                const half8* h1p = (const half8*)&h1c[t & (CHUNK - 1)][g * 32];
                const half8* h2p = (const half8*)&hbuf[cur][g * 32];
                float a0 = 0.f, a1 = 0.f, a2 = 0.f, a3 = 0.f, a4 = 0.f, a5 = 0.f;
                #pragma unroll
                for (int jj = 0; jj < 4; ++jj) {
                    half8 q1 = h1p[jj];
                    half8 q2 = h2p[jj];
                    const hv2* q1v = (const hv2*)&q1;
                    const hv2* q2v = (const hv2*)&q2;
                    #pragma unroll
                    for (int j4 = 0; j4 < 4; ++j4) {
                        const int j = 4 * jj + j4;
                        a0 = dot2f(wih[0][j], q1v[j4], a0);
                        a1 = dot2f(wih[1][j], q1v[j4], a1);
                        a2 = dot2f(wih[2][j], q1v[j4], a2);
                        a3 = dot2f(wih[3][j], q1v[j4], a3);
                        a4 = dot2f(wih[4][j], q1v[j4], a4);
                        a5 = dot2f(wih[5][j], q1v[j4], a5);
                        a0 = dot2f(whh[0][j], q2v[j4], a0);
                        a1 = dot2f(whh[1][j], q2v[j4], a1);
                        a2 = dot2f(whh[2][j], q2v[j4], a2);
                        a3 = dot2f(whh[3][j], q2v[j4], a3);
                        a4 = dot2f(whh[4][j], q2v[j4], a4);
                        a5 = dot2f(whh[5][j], q2v[j4], a5);
                    }
                }
                partials[g][rt]       = a0;
                partials[g][rt + 50]  = a1;
                partials[g][rt + 100] = a2;
                partials[g][rt + 150] = a3;
                partials[g][rt + 200] = a4;
                partials[g][rt + 250] = a5;
            }
            __syncthreads();

            if (tid < 300) {
                float s = bias;
                #pragma unroll
                for (int g2 = 0; g2 < 10; ++g2)
                    s += partials[g2][tid];
                float ht = fast_tanh(s);
                _Float16 hf = (_Float16)ht;
                hbuf[cur ^ 1][tid] = hf;
                H2f[((size_t)(t * BATCH + b)) * 320 + tid] = hf;
            } else if (tid < 320) {
                H2f[((size_t)(t * BATCH + b)) * 320 + tid] = (_Float16)0.f;
            }
            __syncthreads();
            cur ^= 1;
        }
    }
}

extern "C" void kernel_launch(void* const* d_in, const int* in_sizes, int n_in,
                              void* d_out, int out_size, void* d_ws, size_t ws_size,
                              hipStream_t stream) {
    const int*   x     = (const int*)d_in[0];
    const float* emb   = (const float*)d_in[1];
    const float* Wih1  = (const float*)d_in[2];
    const float* Whh1  = (const float*)d_in[3];
    const float* bih1  = (const float*)d_in[4];
    const float* bhh1  = (const float*)d_in[5];
    const float* Wih2  = (const float*)d_in[6];
    const float* Whh2  = (const float*)d_in[7];
    const float* bih2  = (const float*)d_in[8];
    const float* bhh2  = (const float*)d_in[9];
    const float* fc1w  = (const float*)d_in[10];
    const float* fc1b  = (const float*)d_in[11];
    const float* fc2w  = (const float*)d_in[12];
    const float* fc2b  = (const float*)d_in[13];

    float* out1 = (float*)d_out;
    float* out2 = out1 + (size_t)16384 * 128;

    char* w = (char*)d_ws;
    float*        U1    = (float*)w;                   // 19,660,800 B
    _Float16*     H1    = (_Float16*)(w + 19660800);   // 10,485,760 B
    _Float16*     Wf1   = (_Float16*)(w + 30146560);   //  1,024,000 B
    _Float16*     F1    = (_Float16*)(w + 31170560);   //     81,920 B
    _Float16*     F2    = (_Float16*)(w + 31252480);   //     81,920 B
    unsigned int* flags = (unsigned int*)(w + 31334400); //      256 B
    _Float16*     EMBF  = (_Float16*)(w + 31334656);   // 20,480,000 B
    _Float16*     H2    = EMBF;  // reuse: gemm1 done with EMBF before rec writes H2

    const int prep_blocks = (PREP_TOTAL8 + 255) / 256;
    k_prep<<<prep_blocks, 256, 0, stream>>>(emb, Wih1, fc1w, fc2w,
                                            EMBF, Wf1, F1, F2, flags);

    dim3 g(128, 2);
    k_gemm1_mfma<<<g, 256, 0, stream>>>(x, EMBF, Wf1, bih1, bhh1, U1);
    k_rec_fused<<<64, 512, 0, stream>>>(U1, Whh1, Wih2, Whh2, bih2, bhh2,
                                        H1, H2, flags);
    k_fc_mfma<<<g, 256, 0, stream>>>(H1, H2, F1, F2, fc1b, fc2b, out1, out2);
}

// Round 5
// 846.329 us; speedup vs baseline: 2.3516x; 1.0726x over previous
//
#include <hip/hip_runtime.h>
#include <hip/hip_fp16.h>

#define S_LEN 512
#define BATCH 32
#define CHUNK 16

typedef _Float16 hv2  __attribute__((ext_vector_type(2)));
typedef _Float16 half8 __attribute__((ext_vector_type(8)));
typedef float    f32x4 __attribute__((ext_vector_type(4)));

__device__ __forceinline__ float dot2f(hv2 a, hv2 b, float c) {
#if __has_builtin(__builtin_amdgcn_fdot2)
    return __builtin_amdgcn_fdot2(a, b, c, false);
#else
    return c + (float)a.x * (float)b.x + (float)a.y * (float)b.y;
#endif
}

__device__ __forceinline__ float fast_tanh(float x) {
    float e = __expf(2.f * x);
    return 1.f - 2.f / (e + 1.f);
}

// Step barrier that does NOT drain vmcnt: LDS-only visibility.
// Global loads/stores issued around the step loop stay in flight.
__device__ __forceinline__ void lds_barrier() {
    __asm__ volatile("s_waitcnt lgkmcnt(0)\n\ts_barrier" ::: "memory");
}
__device__ __forceinline__ void vm_drain() {
    __asm__ volatile("s_waitcnt vmcnt(0)" ::: "memory");
}

// ---------------------------------------------------------------------------
// Prep: convert to padded f16 (relu fused for emb). Zeroes flags.
// ---------------------------------------------------------------------------
#define E8   1280000   // 32000*320/8
#define W18  64000     // 320*1600/8
#define W28  12800     // 320*320/8
#define FF8  5120      // 128*320/8
#define PREP_TOTAL8 (E8 + W18 + W28 + FF8 + FF8)

__global__ __launch_bounds__(256) void k_prep(
    const float* __restrict__ emb,  const float* __restrict__ Wih1,
    const float* __restrict__ Wih2, const float* __restrict__ fc1w,
    const float* __restrict__ fc2w,
    _Float16* __restrict__ embf, _Float16* __restrict__ Wf1,
    _Float16* __restrict__ Wf2,  _Float16* __restrict__ F1,
    _Float16* __restrict__ F2,   unsigned int* __restrict__ flags)
{
    int gid = blockIdx.x * 256 + threadIdx.x;
    if (gid < 64) flags[gid] = 0u;
    if (gid >= PREP_TOTAL8) return;

    half8 v;
    _Float16* dst;

    if (gid < E8) {
        int row = gid / 40, c8 = (gid - row * 40) * 8;
        #pragma unroll
        for (int j = 0; j < 8; ++j) {
            int c = c8 + j;
            float f = (c < 300) ? emb[(size_t)row * 300 + c] : 0.f;
            v[j] = (_Float16)(f > 0.f ? f : 0.f);
        }
        dst = embf + (size_t)gid * 8;
    } else if (gid < E8 + W18) {
        int i = gid - E8;
        int row = i / 200, c8 = (i - row * 200) * 8;
        #pragma unroll
        for (int j = 0; j < 8; ++j) {
            int c = c8 + j, w = c / 320, cc = c - w * 320;
            float f = (row < 300 && cc < 300) ? Wih1[(size_t)row * 1500 + w * 300 + cc] : 0.f;
            v[j] = (_Float16)f;
        }
        dst = Wf1 + (size_t)i * 8;
    } else if (gid < E8 + W18 + W28) {
        int i = gid - E8 - W18;
        int row = i / 40, c8 = (i - row * 40) * 8;
        #pragma unroll
        for (int j = 0; j < 8; ++j) {
            int c = c8 + j;
            float f = (row < 300 && c < 300) ? Wih2[(size_t)row * 300 + c] : 0.f;
            v[j] = (_Float16)f;
        }
        dst = Wf2 + (size_t)i * 8;
    } else if (gid < E8 + W18 + W28 + FF8) {
        int i = gid - E8 - W18 - W28;
        int row = i / 40, c8 = (i - row * 40) * 8;
        #pragma unroll
        for (int j = 0; j < 8; ++j) {
            int c = c8 + j;
            v[j] = (_Float16)((c < 300) ? fc1w[(size_t)row * 300 + c] : 0.f);
        }
        dst = F1 + (size_t)i * 8;
    } else {
        int i = gid - E8 - W18 - W28 - FF8;
        int row = i / 40, c8 = (i - row * 40) * 8;
        #pragma unroll
        for (int j = 0; j < 8; ++j) {
            int c = c8 + j;
            v[j] = (_Float16)((c < 300) ? fc2w[(size_t)row * 300 + c] : 0.f);
        }
        dst = F2 + (size_t)i * 8;
    }
    *(half8*)dst = v;
}

// ---------------------------------------------------------------------------
// GEMM1 (MFMA, fused embedding gather). grid (128,2), block 256.
// ---------------------------------------------------------------------------
__global__ __launch_bounds__(256) void k_gemm1_mfma(
    const int* __restrict__ x, const _Float16* __restrict__ embf,
    const _Float16* __restrict__ Wf1, const float* __restrict__ b1,
    const float* __restrict__ b2, float* __restrict__ U)
{
    const int wid  = threadIdx.x >> 6;
    const int lane = threadIdx.x & 63;
    const int m    = lane & 15;
    const int q    = lane >> 4;
    const int r0   = blockIdx.x * 128 + wid * 32;
    const int n0   = blockIdx.y * 160;

    f32x4 acc[2][10];
    #pragma unroll
    for (int i = 0; i < 2; ++i)
        #pragma unroll
        for (int j = 0; j < 10; ++j)
            acc[i][j] = (f32x4){0.f, 0.f, 0.f, 0.f};

    const int rA = r0 + m, rB = r0 + 16 + m;
    const int xbA = ((rA & 31) * S_LEN + (rA >> 5)) * 5;
    const int xbB = ((rB & 31) * S_LEN + (rB >> 5)) * 5;

    for (int w = 0; w < 5; ++w) {
        const int idxA = x[xbA + w];
        const int idxB = x[xbB + w];
        const _Float16* ea = embf + (size_t)idxA * 320;
        const _Float16* eb = embf + (size_t)idxB * 320;
        const _Float16* wb = Wf1 + (size_t)w * 320;
        #pragma unroll
        for (int c = 0; c < 10; ++c) {
            const int k = c * 32 + q * 8;
            half8 a0 = *(const half8*)(ea + k);
            half8 a1 = *(const half8*)(eb + k);
            #pragma unroll
            for (int nt = 0; nt < 10; ++nt) {
                half8 bf = *(const half8*)(wb + (size_t)(n0 + nt * 16 + m) * 1600 + k);
                acc[0][nt] = __builtin_amdgcn_mfma_f32_16x16x32_f16(a0, bf, acc[0][nt], 0, 0, 0);
                acc[1][nt] = __builtin_amdgcn_mfma_f32_16x16x32_f16(a1, bf, acc[1][nt], 0, 0, 0);
            }
        }
    }

    #pragma unroll
    for (int nt = 0; nt < 10; ++nt) {
        const int n = n0 + nt * 16 + m;
        if (n >= 300) continue;
        const float bias = b1[n] + b2[n];
        #pragma unroll
        for (int mt = 0; mt < 2; ++mt) {
            const int rbase = r0 + mt * 16 + q * 4;
            #pragma unroll
            for (int reg = 0; reg < 4; ++reg)
                U[(size_t)(rbase + reg) * 300 + n] = acc[mt][nt][reg] + bias;
        }
    }
}

// ---------------------------------------------------------------------------
// FC (MFMA): per-wave 32x128. grid (128, 2): y = layer.
// ---------------------------------------------------------------------------
__global__ __launch_bounds__(256) void k_fc_mfma(
    const _Float16* __restrict__ H1, const _Float16* __restrict__ H2,
    const _Float16* __restrict__ F1, const _Float16* __restrict__ F2,
    const float* __restrict__ fb1, const float* __restrict__ fb2,
    float* __restrict__ out1, float* __restrict__ out2)
{
    const int layer = blockIdx.y;
    const _Float16* H = layer ? H2 : H1;
    const _Float16* F = layer ? F2 : F1;
    const float* bias = layer ? fb2 : fb1;
    float* out        = layer ? out2 : out1;

    const int wid  = threadIdx.x >> 6;
    const int lane = threadIdx.x & 63;
    const int m    = lane & 15;
    const int q    = lane >> 4;
    const int r0   = blockIdx.x * 128 + wid * 32;

    f32x4 acc[2][8];
    #pragma unroll
    for (int i = 0; i < 2; ++i)
        #pragma unroll
        for (int j = 0; j < 8; ++j)
            acc[i][j] = (f32x4){0.f, 0.f, 0.f, 0.f};

    const _Float16* ha = H + (size_t)(r0 + m) * 320;
    const _Float16* hb = H + (size_t)(r0 + 16 + m) * 320;

    #pragma unroll
    for (int c = 0; c < 10; ++c) {
        const int k = c * 32 + q * 8;
        half8 a0 = *(const half8*)(ha + k);
        half8 a1 = *(const half8*)(hb + k);
        #pragma unroll
        for (int nt = 0; nt < 8; ++nt) {
            half8 bf = *(const half8*)(F + (size_t)(nt * 16 + m) * 320 + k);
            acc[0][nt] = __builtin_amdgcn_mfma_f32_16x16x32_f16(a0, bf, acc[0][nt], 0, 0, 0);
            acc[1][nt] = __builtin_amdgcn_mfma_f32_16x16x32_f16(a1, bf, acc[1][nt], 0, 0, 0);
        }
    }

    #pragma unroll
    for (int nt = 0; nt < 8; ++nt) {
        const int n = nt * 16 + m;
        const float bv = bias[n];
        #pragma unroll
        for (int mt = 0; mt < 2; ++mt) {
            #pragma unroll
            for (int reg = 0; reg < 4; ++reg) {
                const int r = r0 + mt * 16 + q * 4 + reg;
                const int oidx = ((r & 31) * S_LEN + (r >> 5)) * 128 + n;
                out[oidx] = acc[mt][nt][reg] + bv;
            }
        }
    }
}

// ---------------------------------------------------------------------------
// Fused recurrence, chunked LDS-resident pipeline. 64 blocks x 512 threads.
//  Blocks 0..31 (producer, layer1): per chunk of 16 steps:
//    [bulk-store prev H1 chunk; ds_write U-chunk from prefetch regs;
//     vm_drain + flag release; issue next U prefetch] then 16 LDS-only steps
//    with lgkm-only barriers (global prefetch stays in flight).
//  Blocks 32..63 (consumer, layer2): per chunk: wait flag; stage h1 chunk;
//    MFMA [16x320]@Wf2^T -> U2 in LDS; 16 LDS-only steps (96 dot2 Whh2).
// Dynamic LDS layout (byte offsets):
//   partials float[10][304]      @ 0      (12160)
//   hc       f16  [16][320]      @ 12160  (10240)  h-state ring (h1 / h2)
//   uc       f32  [16][304]      @ 22400  (19456)  U1-chunk / U2-chunk
//   h1s      f16  [16][320]      @ 41856  (10240)  consumer-only staged h1
// ---------------------------------------------------------------------------
#define LDS_BYTES 52096

__device__ __forceinline__ void load_u_regs(float* up, const float* __restrict__ U1,
                                            int b, int t0) {
    #pragma unroll
    for (int j = 0; j < 10; ++j) {
        int e = threadIdx.x + 512 * j;
        int row = e / 300, col = e - row * 300;
        up[j] = (e < 4800) ? U1[((size_t)((t0 + row) * BATCH + b)) * 300 + col] : 0.f;
    }
}

__global__ __launch_bounds__(512) void k_rec_fused(
    const float* __restrict__ U1, const float* __restrict__ Whh1,
    const _Float16* __restrict__ Wf2, const float* __restrict__ Whh2,
    const float* __restrict__ bih2, const float* __restrict__ bhh2,
    _Float16* __restrict__ H1f, _Float16* __restrict__ H2f,
    unsigned int* __restrict__ flags)
{
    extern __shared__ char smem[];
    float   (*partials)[304] = (float(*)[304])smem;
    _Float16 (*hc)[320]      = (_Float16(*)[320])(smem + 12160);
    float   (*uc)[304]       = (float(*)[304])(smem + 22400);
    _Float16 (*h1s)[320]     = (_Float16(*)[320])(smem + 41856);

    const int tid  = threadIdx.x;
    const bool comp = tid < 500;
    const int g    = comp ? tid / 50 : 0;
    const int rt   = comp ? tid % 50 : 0;
    const int lane = tid & 63;
    const int wid  = tid >> 6;
    const int lm   = lane & 15;
    const int lq   = lane >> 4;

    // zero h ring (slot 15 = h_{-1} = 0; pad cols stay 0 forever)
    for (int i = tid; i < CHUNK * 320; i += 512)
        ((_Float16*)hc)[i] = (_Float16)0.f;

    if (blockIdx.x < 32) {
        // ========================= producer: layer 1 =========================
        const int b = blockIdx.x;
        hv2 w1[6][16];
        if (comp) {
            #pragma unroll
            for (int i = 0; i < 6; ++i) {
                const float* wr = Whh1 + (size_t)(rt + 50 * i) * 300 + g * 32;
                #pragma unroll
                for (int j = 0; j < 16; ++j) {
                    int c0 = g * 32 + 2 * j;
                    hv2 p;
                    p.x = (c0     < 300) ? (_Float16)wr[2 * j]     : (_Float16)0.f;
                    p.y = (c0 + 1 < 300) ? (_Float16)wr[2 * j + 1] : (_Float16)0.f;
                    w1[i][j] = p;
                }
            }
        }

        float upref[10];
        load_u_regs(upref, U1, b, 0);

        for (int c = 0; c < 32; ++c) {
            const int t0 = c * CHUNK;
            if (c > 0) {
                // bulk-store previous chunk's H1 (regs hold data before overwrite)
                const int tb = t0 - CHUNK;
                for (int i = tid; i < CHUNK * 40; i += 512) {
                    int row = i / 40, c8 = i - row * 40;
                    half8 v = *(const half8*)&hc[row][c8 * 8];
                    *(half8*)&H1f[((size_t)((tb + row) * BATCH + b)) * 320 + c8 * 8] = v;
                }
            }
            // stage this chunk's U into LDS from prefetch regs
            #pragma unroll
            for (int j = 0; j < 10; ++j) {
                int e = tid + 512 * j;
                if (e < 4800) {
                    int row = e / 300, col = e - row * 300;
                    uc[row][col] = upref[j];
                }
            }
            if (c > 0) {
                vm_drain();   // H1 stores complete before release
                if (tid == 0)
                    __hip_atomic_store(&flags[b], (unsigned)t0,
                                       __ATOMIC_RELEASE, __HIP_MEMORY_SCOPE_AGENT);
            }
            if (c + 1 < 32)
                load_u_regs(upref, U1, b, t0 + CHUNK);   // in flight across steps
            lds_barrier();

            for (int s = 0; s < CHUNK; ++s) {
                if (comp) {
                    const half8* hp = (const half8*)&hc[(s - 1) & 15][g * 32];
                    float a0 = 0.f, a1 = 0.f, a2 = 0.f, a3 = 0.f, a4 = 0.f, a5 = 0.f;
                    #pragma unroll
                    for (int jj = 0; jj < 4; ++jj) {
                        half8 q8 = hp[jj];
                        const hv2* qv = (const hv2*)&q8;
                        #pragma unroll
                        for (int j4 = 0; j4 < 4; ++j4) {
                            const int j = 4 * jj + j4;
                            a0 = dot2f(w1[0][j], qv[j4], a0);
                            a1 = dot2f(w1[1][j], qv[j4], a1);
                            a2 = dot2f(w1[2][j], qv[j4], a2);
                            a3 = dot2f(w1[3][j], qv[j4], a3);
                            a4 = dot2f(w1[4][j], qv[j4], a4);
                            a5 = dot2f(w1[5][j], qv[j4], a5);
                        }
                    }
                    partials[g][rt]       = a0;
                    partials[g][rt + 50]  = a1;
                    partials[g][rt + 100] = a2;
                    partials[g][rt + 150] = a3;
                    partials[g][rt + 200] = a4;
                    partials[g][rt + 250] = a5;
                }
                lds_barrier();
                if (tid < 300) {
                    float ssum = uc[s][tid];
                    #pragma unroll
                    for (int g2 = 0; g2 < 10; ++g2)
                        ssum += partials[g2][tid];
                    hc[s][tid] = (_Float16)fast_tanh(ssum);
                }
                lds_barrier();
            }
        }
        // final chunk store + flag
        {
            const int tb = S_LEN - CHUNK;
            for (int i = tid; i < CHUNK * 40; i += 512) {
                int row = i / 40, c8 = i - row * 40;
                half8 v = *(const half8*)&hc[row][c8 * 8];
                *(half8*)&H1f[((size_t)((tb + row) * BATCH + b)) * 320 + c8 * 8] = v;
            }
            vm_drain();
            if (tid == 0)
                __hip_atomic_store(&flags[b], (unsigned)S_LEN,
                                   __ATOMIC_RELEASE, __HIP_MEMORY_SCOPE_AGENT);
        }
    } else {
        // ========================= consumer: layer 2 =========================
        const int b = blockIdx.x - 32;
        hv2 whh[6][16];
        if (comp) {
            #pragma unroll
            for (int i = 0; i < 6; ++i) {
                const float* wr = Whh2 + (size_t)(rt + 50 * i) * 300 + g * 32;
                #pragma unroll
                for (int j = 0; j < 16; ++j) {
                    int c0 = g * 32 + 2 * j;
                    hv2 p;
                    p.x = (c0     < 300) ? (_Float16)wr[2 * j]     : (_Float16)0.f;
                    p.y = (c0 + 1 < 300) ? (_Float16)wr[2 * j + 1] : (_Float16)0.f;
                    whh[i][j] = p;
                }
            }
        }
        float bias = (tid < 300) ? (bih2[tid] + bhh2[tid]) : 0.f;

        for (int c = 0; c < 32; ++c) {
            const int t0 = c * CHUNK;
            if (c > 0) {
                const int tb = t0 - CHUNK;
                for (int i = tid; i < CHUNK * 40; i += 512) {
                    int row = i / 40, c8 = i - row * 40;
                    half8 v = *(const half8*)&hc[row][c8 * 8];
                    *(half8*)&H2f[((size_t)((tb + row) * BATCH + b)) * 320 + c8 * 8] = v;
                }
            }
            if (tid == 0) {
                while (__hip_atomic_load(&flags[b], __ATOMIC_ACQUIRE,
                                         __HIP_MEMORY_SCOPE_AGENT) < (unsigned)(t0 + CHUNK))
                    __builtin_amdgcn_s_sleep(2);
            }
            __syncthreads();   // orders after poll; drains H2 stores (once/chunk)

            // stage this chunk's h1 into LDS
            for (int i = tid; i < CHUNK * 40; i += 512) {
                int row = i / 40, c8 = i - row * 40;
                *(half8*)&h1s[row][c8 * 8] =
                    *(const half8*)&H1f[((size_t)((t0 + row) * BATCH + b)) * 320 + c8 * 8];
            }
            lds_barrier();

            // U2-chunk = h1s @ Wf2^T via MFMA (M=16 steps, N=304, K=320)
            for (int nt = wid; nt < 19; nt += 8) {
                f32x4 acc = (f32x4){0.f, 0.f, 0.f, 0.f};
                const int n = nt * 16 + lm;
                const _Float16* wrow = Wf2 + (size_t)n * 320;
                #pragma unroll
                for (int k0 = 0; k0 < 320; k0 += 32) {
                    half8 a  = *(const half8*)&h1s[lm][k0 + lq * 8];
                    half8 bf = *(const half8*)&wrow[k0 + lq * 8];
                    acc = __builtin_amdgcn_mfma_f32_16x16x32_f16(a, bf, acc, 0, 0, 0);
                }
                #pragma unroll
                for (int reg = 0; reg < 4; ++reg)
                    uc[lq * 4 + reg][n] = acc[reg];
            }
            lds_barrier();

            for (int s = 0; s < CHUNK; ++s) {
                if (comp) {
                    const half8* hp = (const half8*)&hc[(s - 1) & 15][g * 32];
                    float a0 = 0.f, a1 = 0.f, a2 = 0.f, a3 = 0.f, a4 = 0.f, a5 = 0.f;
                    #pragma unroll
                    for (int jj = 0; jj < 4; ++jj) {
                        half8 q8 = hp[jj];
                        const hv2* qv = (const hv2*)&q8;
                        #pragma unroll
                        for (int j4 = 0; j4 < 4; ++j4) {
                            const int j = 4 * jj + j4;
                            a0 = dot2f(whh[0][j], qv[j4], a0);
                            a1 = dot2f(whh[1][j], qv[j4], a1);
                            a2 = dot2f(whh[2][j], qv[j4], a2);
                            a3 = dot2f(whh[3][j], qv[j4], a3);
                            a4 = dot2f(whh[4][j], qv[j4], a4);
                            a5 = dot2f(whh[5][j], qv[j4], a5);
                        }
                    }
                    partials[g][rt]       = a0;
                    partials[g][rt + 50]  = a1;
                    partials[g][rt + 100] = a2;
                    partials[g][rt + 150] = a3;
                    partials[g][rt + 200] = a4;
                    partials[g][rt + 250] = a5;
                }
                lds_barrier();
                if (tid < 300) {
                    float ssum = bias + uc[s][tid];
                    #pragma unroll
                    for (int g2 = 0; g2 < 10; ++g2)
                        ssum += partials[g2][tid];
                    hc[s][tid] = (_Float16)fast_tanh(ssum);
                }
                lds_barrier();
            }
        }
        // final H2 chunk store
        {
            const int tb = S_LEN - CHUNK;
            for (int i = tid; i < CHUNK * 40; i += 512) {
                int row = i / 40, c8 = i - row * 40;
                half8 v = *(const half8*)&hc[row][c8 * 8];
                *(half8*)&H2f[((size_t)((tb + row) * BATCH + b)) * 320 + c8 * 8] = v;
            }
        }
    }
}

extern "C" void kernel_launch(void* const* d_in, const int* in_sizes, int n_in,
                              void* d_out, int out_size, void* d_ws, size_t ws_size,
                              hipStream_t stream) {
    const int*   x     = (const int*)d_in[0];
    const float* emb   = (const float*)d_in[1];
    const float* Wih1  = (const float*)d_in[2];
    const float* Whh1  = (const float*)d_in[3];
    const float* bih1  = (const float*)d_in[4];
    const float* bhh1  = (const float*)d_in[5];
    const float* Wih2  = (const float*)d_in[6];
    const float* Whh2  = (const float*)d_in[7];
    const float* bih2  = (const float*)d_in[8];
    const float* bhh2  = (const float*)d_in[9];
    const float* fc1w  = (const float*)d_in[10];
    const float* fc1b  = (const float*)d_in[11];
    const float* fc2w  = (const float*)d_in[12];
    const float* fc2b  = (const float*)d_in[13];

    float* out1 = (float*)d_out;
    float* out2 = out1 + (size_t)16384 * 128;

    char* w = (char*)d_ws;
    float*        U1    = (float*)w;                     // 19,660,800
    _Float16*     H1    = (_Float16*)(w + 19660800);     // 10,485,760
    _Float16*     Wf1   = (_Float16*)(w + 30146560);     //  1,024,000
    _Float16*     Wf2   = (_Float16*)(w + 31170560);     //    204,800
    _Float16*     F1    = (_Float16*)(w + 31375360);     //     81,920
    _Float16*     F2    = (_Float16*)(w + 31457280);     //     81,920
    unsigned int* flags = (unsigned int*)(w + 31539200); //        256
    _Float16*     EMBF  = (_Float16*)(w + 31539456);     // 20,480,000
    _Float16*     H2    = EMBF;  // reuse: gemm1 done with EMBF before rec writes H2

    const int prep_blocks = (PREP_TOTAL8 + 255) / 256;
    k_prep<<<prep_blocks, 256, 0, stream>>>(emb, Wih1, Wih2, fc1w, fc2w,
                                            EMBF, Wf1, Wf2, F1, F2, flags);

    dim3 g(128, 2);
    k_gemm1_mfma<<<g, 256, 0, stream>>>(x, EMBF, Wf1, bih1, bhh1, U1);
    k_rec_fused<<<64, 512, LDS_BYTES, stream>>>(U1, Whh1, Wf2, Whh2, bih2, bhh2,
                                                H1, H2, flags);
    k_fc_mfma<<<g, 256, 0, stream>>>(H1, H2, F1, F2, fc1b, fc2b, out1, out2);
}